// Round 15
// baseline (3663.578 us; speedup 1.0000x reference)
//
#include <hip/hip_runtime.h>

#define N_PTS 8192
#define M_PTS 2048
#define K_NN 16
#define IN_CH 64
#define G_CH 68
#define OUT_CH 128
#define KC 192            // candidate cap per query (E~110, ~8 sigma headroom)
#define NWK 63            // worker blocks per batch
#define CHQ 16            // queries per chunk
#define NCHUNK (M_PTS / CHQ)   // 128 chunks per batch

// Unfusable fp32 ops: inline asm cannot be FMA-contracted by the compiler.
__device__ __forceinline__ float subrn(float a, float b) {
    float r; asm("v_sub_f32 %0, %1, %2" : "=v"(r) : "v"(a), "v"(b)); return r;
}
__device__ __forceinline__ float mulrn(float a, float b) {
    float r; asm("v_mul_f32 %0, %1, %2" : "=v"(r) : "v"(a), "v"(b)); return r;
}
__device__ __forceinline__ float addrn(float a, float b) {
    float r; asm("v_add_f32 %0, %1, %2" : "=v"(r) : "v"(a), "v"(b)); return r;
}
// numpy-exact fp32 squared distance: ((dx*dx + dy*dy) + dz*dz), per-op rounding.
__device__ __forceinline__ float sqdist_rn(float ax, float ay, float az,
                                           float bx, float by, float bz) {
    float dx = subrn(ax, bx);
    float dy = subrn(ay, by);
    float dz = subrn(az, bz);
    return addrn(addrn(mulrn(dx, dx), mulrn(dy, dy)), mulrn(dz, dz));
}

// Packed 2xfp32 ops (VOP3P): each half a plain IEEE fp32 op (bit-identical).
typedef float v2f __attribute__((ext_vector_type(2)));
__device__ __forceinline__ v2f pk_add(v2f a, v2f b) {
    v2f r; asm("v_pk_add_f32 %0, %1, %2" : "=v"(r) : "v"(a), "v"(b)); return r;
}
__device__ __forceinline__ v2f pk_mul(v2f a, v2f b) {
    v2f r; asm("v_pk_mul_f32 %0, %1, %2" : "=v"(r) : "v"(a), "v"(b)); return r;
}

// ---- DPP helpers ----------------------------------------------------------
template <int CTRL>
__device__ __forceinline__ float movdpp_f(float x) {
    int r = __builtin_amdgcn_mov_dpp(__float_as_int(x), CTRL, 0xf, 0xf, true);
    return __int_as_float(r);
}
template <int CTRL, int RM>
__device__ __forceinline__ float dppmaxf_m(float x) {
    int r = __builtin_amdgcn_update_dpp(0, __float_as_int(x), CTRL, RM, 0xf, false);
    return fmaxf(x, __int_as_float(r));   // old=0 safe: dists >= 0
}
__device__ __forceinline__ float wave_max64(float x) {
    x = fmaxf(x, movdpp_f<0xB1>(x));
    x = fmaxf(x, movdpp_f<0x4E>(x));
    x = fmaxf(x, movdpp_f<0x141>(x));
    x = fmaxf(x, movdpp_f<0x140>(x));
    x = dppmaxf_m<0x142, 0xa>(x);
    x = dppmaxf_m<0x143, 0xc>(x);
    return x;
}
__device__ __forceinline__ float group8_max(float x) {
    x = fmaxf(x, movdpp_f<0xB1>(x));
    x = fmaxf(x, movdpp_f<0x4E>(x));
    x = fmaxf(x, movdpp_f<0x141>(x));
    return x;
}
// 16-lane row max then cross-row (xor16) -> 32-lane-group max (lane%32-aligned)
__device__ __forceinline__ float group32_max(float x) {
    x = fmaxf(x, movdpp_f<0xB1>(x));
    x = fmaxf(x, movdpp_f<0x4E>(x));
    x = fmaxf(x, movdpp_f<0x141>(x));
    x = fmaxf(x, movdpp_f<0x140>(x));
    x = fmaxf(x, __shfl_xor(x, 16));
    return x;
}

// ---------------------------------------------------------------------------
// Fused kernel: 4 fps blocks + 252 workers. R14 failed because fps published
// down_idx EVERY iteration -> __syncthreads' vmcnt(0) drain put the global
// store on the 2047-long serial path (+1970 cyc/iter). R15 batches: indices
// stay in LDS; every 128 iters threads 0-127 flush + threadfence + barrier +
// one agent-release of prog (16 flushes total). Loop body = R13 shape.
// ---------------------------------------------------------------------------
__global__ __launch_bounds__(512, 2) void fused_kernel(
        const float4* __restrict__ events4,
        const float4* __restrict__ feat4,
        const float*  __restrict__ W,
        const float*  __restrict__ bias,
        int*   __restrict__ down_idx,
        int*   __restrict__ prog,
        float4* __restrict__ out_de,
        float* __restrict__ hmax_g,
        float* __restrict__ hmin_g,
        float* __restrict__ gsum,
        float* __restrict__ gsq) {
    extern __shared__ char smem[];
    const int tid = threadIdx.x;

    if (blockIdx.x < 4) {
        // ================= FPS role =====
        float*  rv   = (float*)smem;                   // 8 floats
        int*    wsl  = (int*)(smem + 32);              // 2 ints (parity)
        int*    ssel = (int*)(smem + 64);              // 2048 ints
        float4* spt  = (float4*)(smem + 64 + 4 * M_PTS);

        const int b = blockIdx.x;
        const int wave = tid >> 6;
        const int lane = tid & 63;
        const float4* ev = events4 + (size_t)b * N_PTS;

        for (int i = tid; i < N_PTS; i += 512) spt[i] = ev[i];
        if (tid == 0) { ssel[0] = 0; wsl[0] = 0x7fffffff; wsl[1] = 0x7fffffff; }
        __syncthreads();

        v2f px[8], py[8], pz[8];
        float dist[16];
#pragma unroll
        for (int pp = 0; pp < 8; ++pp) {
            float4 f0 = spt[(2 * pp) * 512 + tid];
            float4 f1 = spt[(2 * pp + 1) * 512 + tid];
            px[pp] = (v2f){f0.x, f1.x};
            py[pp] = (v2f){f0.y, f1.y};
            pz[pp] = (v2f){f0.z, f1.z};
            dist[2 * pp] = 1e10f; dist[2 * pp + 1] = 1e10f;   // reference init
        }

        int last = 0;
        for (int i = 1; i < M_PTS; ++i) {
            float4 L = spt[last];
            const float nlx = -L.x, nly = -L.y, nlz = -L.z;   // exact sign flips
            const v2f nx2 = (v2f){nlx, nlx};
            const v2f ny2 = (v2f){nly, nly};
            const v2f nz2 = (v2f){nlz, nlz};
#pragma unroll
            for (int pp = 0; pp < 8; ++pp) {
                v2f dx = pk_add(px[pp], nx2);
                v2f dy = pk_add(py[pp], ny2);
                v2f dz = pk_add(pz[pp], nz2);
                v2f s  = pk_add(pk_add(pk_mul(dx, dx), pk_mul(dy, dy)), pk_mul(dz, dz));
                dist[2 * pp]     = fminf(dist[2 * pp],     s.x);
                dist[2 * pp + 1] = fminf(dist[2 * pp + 1], s.y);
            }
            float t0[8];
#pragma unroll
            for (int j = 0; j < 8; ++j) t0[j] = fmaxf(dist[2 * j], dist[2 * j + 1]);
#pragma unroll
            for (int j = 0; j < 4; ++j) t0[j] = fmaxf(t0[2 * j], t0[2 * j + 1]);
            float bd = fmaxf(fmaxf(t0[0], t0[1]), fmaxf(t0[2], t0[3]));

            float wm = wave_max64(bd);
            if (lane == 63) rv[wave] = wm;
            __syncthreads();                          // B1
            float bm = group8_max(rv[lane & 7]);

            if (bd == bm) {
                int jm = 0;
#pragma unroll
                for (int j = 15; j >= 0; --j) if (dist[j] == bd) jm = j;
                atomicMin(&wsl[i & 1], jm * 512 + tid);
            }
            __syncthreads();                          // B2
            last = wsl[i & 1];
            if (tid == 0) { ssel[i] = last; wsl[(i + 1) & 1] = 0x7fffffff; }

            // batched publish: 16 flushes total, off the per-iter serial path
            if ((i & 127) == 127) {
                __syncthreads();                      // ssel[i] visible
                if (tid < 128)
                    down_idx[b * M_PTS + (i - 127) + tid] = ssel[(i - 127) + tid];
                __threadfence();
                __syncthreads();                      // vmcnt drain: stores done
                if (tid == 0)
                    __hip_atomic_store(prog + b, i + 1, __ATOMIC_RELEASE,
                                       __HIP_MEMORY_SCOPE_AGENT);
            }
        }
        __syncthreads();

        for (int i = tid; i < M_PTS; i += 512) {
            out_de[(size_t)b * M_PTS + i] = spt[ssel[i]];
        }
        return;
    }

    // ================= Worker role: streamed kNN + gather/matmul ===========
    float2* sxy  = (float2*)smem;                         // 65536 B
    float*  szl  = (float*)(smem + 65536);                // 32768 B
    float*  cd   = (float*)(smem + 98304);                // 16*KC*4
    int*    ci   = (int*)(smem + 98304 + 16 * KC * 4);    // 16*KC*4
    int*    scnt = (int*)(smem + 98304 + 32 * KC * 4);    // 64 B
    int*    sqi  = (int*)(smem + 98304 + 32 * KC * 4 + 64);   // 64 B
    int*    sk   = (int*)(smem + 98304 + 32 * KC * 4 + 128);  // 1024 B
    float4* sg4  = (float4*)(smem + 98304 + 32 * KC * 4 + 1152); // 4*16*17*16 B

    const int wk = blockIdx.x - 4;
    const int b  = wk / NWK;
    const int w  = wk - b * NWK;
    const int ql   = tid >> 5;     // 0..15 local query
    const int part = tid & 31;     // 32 point-partitions per query
    const int d  = tid & 127;
    const int qs = tid >> 7;       // 0..3 gmm query slot

    const float4* ev = events4 + (size_t)b * N_PTS;
    for (int i = tid; i < N_PTS; i += 512) {
        float4 e = ev[i];
        sxy[i] = (float2){e.x, e.y}; szl[i] = e.z;
    }

    float wreg[G_CH];
#pragma unroll
    for (int c = 0; c < G_CH; ++c) wreg[c] = W[c * OUT_CH + d];
    const float breg = bias[d];
    float ssum = 0.f, ssq = 0.f;

    const float4* sxy4 = (const float4*)sxy;
    const float2* sz2  = (const float2*)szl;

    for (int s = 0; s < 3; ++s) {
        const int c = w + s * NWK;          // chunks w, w+63, w+126
        if (c >= NCHUNK) break;
        const int need = (c + 1) * CHQ;
        while (__hip_atomic_load(prog + b, __ATOMIC_ACQUIRE,
                                 __HIP_MEMORY_SCOPE_AGENT) < need)
            __builtin_amdgcn_s_sleep(64);
        if (tid < CHQ) scnt[tid] = 0;
        __syncthreads();                     // coords staged + scnt zeroed

        const int q  = c * CHQ + ql;
        const int qi = down_idx[b * M_PTS + q];
        const float2 qxy = sxy[qi];
        const float qx = qxy.x, qy = qxy.y, qz = szl[qi];

        // pass 1: per-lane min over 256 pts (128 adjacent pairs)
        float m1 = 1e30f;
        for (int i = 0; i < 128; ++i) {
            const int ph = i * 32 + part;
            float4 xy = sxy4[ph];
            float2 zz = sz2[ph];
            float d0 = sqdist_rn(xy.x, xy.y, zz.x, qx, qy, qz);
            float d1 = sqdist_rn(xy.z, xy.w, zz.y, qx, qy, qz);
            m1 = fminf(m1, fminf(d0, d1));
        }
        // T = max of 32 lane-minima >= 32nd distance >= 16th distance
        const float T = group32_max(m1);

        // pass 2: compact candidates d <= T
        for (int i = 0; i < 128; ++i) {
            const int ph = i * 32 + part;
            float4 xy = sxy4[ph];
            float2 zz = sz2[ph];
            float d0 = sqdist_rn(xy.x, xy.y, zz.x, qx, qy, qz);
            float d1 = sqdist_rn(xy.z, xy.w, zz.y, qx, qy, qz);
            if (d0 <= T) {
                int pos = atomicAdd(&scnt[ql], 1);
                if (pos < KC) { cd[ql * KC + pos] = d0; ci[ql * KC + pos] = 2 * ph; }
            }
            if (d1 <= T) {
                int pos = atomicAdd(&scnt[ql], 1);
                if (pos < KC) { cd[ql * KC + pos] = d1; ci[ql * KC + pos] = 2 * ph + 1; }
            }
        }
        __syncthreads();

        // exact stable top-16 (lexicographic (d, idx)); order-invariant set
        if (part == 0) {
            float nd[16]; int ni[16];
#pragma unroll
            for (int j = 0; j < 16; ++j) { nd[j] = 1e30f; ni[j] = 0x7fffffff; }
            float wmax = 1e30f; int widx = 0x7fffffff; int wslot = 0;
            const int n = scnt[ql];
            const int lim = (n <= KC) ? n : 0;
            for (int t = 0; t < lim; ++t) {
                float dv = cd[ql * KC + t];
                int   p  = ci[ql * KC + t];
                if (dv < wmax || (dv == wmax && p < widx)) {
#pragma unroll
                    for (int j = 0; j < 16; ++j) if (j == wslot) { nd[j] = dv; ni[j] = p; }
                    float m_ = -1.0f; int mix_ = -1; int ms_ = 0;
#pragma unroll
                    for (int j = 0; j < 16; ++j)
                        if (nd[j] > m_ || (nd[j] == m_ && ni[j] > mix_)) { m_ = nd[j]; mix_ = ni[j]; ms_ = j; }
                    wmax = m_; widx = mix_; wslot = ms_;
                }
            }
            if (n > KC) {   // exact serial fallback (never expected)
                for (int p = 0; p < N_PTS; ++p) {
                    float2 pxy = sxy[p];
                    float dv = sqdist_rn(pxy.x, pxy.y, szl[p], qx, qy, qz);
                    if (dv < wmax || (dv == wmax && p < widx)) {
#pragma unroll
                        for (int j = 0; j < 16; ++j) if (j == wslot) { nd[j] = dv; ni[j] = p; }
                        float m_ = -1.0f; int mix_ = -1; int ms_ = 0;
#pragma unroll
                        for (int j = 0; j < 16; ++j)
                            if (nd[j] > m_ || (nd[j] == m_ && ni[j] > mix_)) { m_ = nd[j]; mix_ = ni[j]; ms_ = j; }
                        wmax = m_; widx = mix_; wslot = ms_;
                    }
                }
            }
            sqi[ql] = qi;
#pragma unroll
            for (int j = 0; j < 16; ++j) sk[ql * 16 + j] = ni[j];
        }
        __syncthreads();

        // gmm: 4 rounds x 4 queries; thread = (d, qs) does all 16 k's
        for (int r4 = 0; r4 < 4; ++r4) {
            for (int j4 = tid; j4 < 4 * 16 * 17; j4 += 512) {
                int qq  = j4 / 272;
                int rem = j4 - qq * 272;
                int k   = rem / 17;
                int c4  = rem - k * 17;
                int qlo = r4 * 4 + qq;
                int nb  = sk[qlo * 16 + k];
                float4 v;
                if (c4 == 0) {
                    float4 e  = events4[(size_t)b * N_PTS + nb];
                    float4 d0 = events4[(size_t)b * N_PTS + sqi[qlo]];
                    v = (float4){e.x - d0.x, e.y - d0.y, e.z - d0.z, e.w - d0.w};
                } else {
                    v = feat4[((size_t)(b * N_PTS + nb)) * 16 + (c4 - 1)];
                }
                sg4[j4] = v;
            }
            __syncthreads();

            const int qlo = r4 * 4 + qs;
            float hmax = -1e30f, hmin = 1e30f;
#pragma unroll
            for (int k = 0; k < 16; ++k) {
                float acc = breg;
#pragma unroll
                for (int c4 = 0; c4 < 17; ++c4) {
                    float4 g = sg4[qs * 272 + k * 17 + c4];
                    acc = fmaf(g.x, wreg[4 * c4 + 0], acc);
                    acc = fmaf(g.y, wreg[4 * c4 + 1], acc);
                    acc = fmaf(g.z, wreg[4 * c4 + 2], acc);
                    acc = fmaf(g.w, wreg[4 * c4 + 3], acc);
                }
                hmax = fmaxf(hmax, acc);
                hmin = fminf(hmin, acc);
                ssum += acc;
                ssq = fmaf(acc, acc, ssq);
            }
            const size_t o = ((size_t)(b * M_PTS + c * CHQ + qlo)) * OUT_CH + d;
            hmax_g[o] = hmax;
            hmin_g[o] = hmin;
            __syncthreads();
        }
    }

    // block-combine BN partials (reuse cd region), 1 atomic per channel x2
    float* red = cd;
    red[tid] = ssum;
    __syncthreads();
    if (tid < 128) atomicAdd(&gsum[tid], red[tid] + red[tid + 128] + red[tid + 256] + red[tid + 384]);
    __syncthreads();
    red[tid] = ssq;
    __syncthreads();
    if (tid < 128) atomicAdd(&gsq[tid],  red[tid] + red[tid + 128] + red[tid + 256] + red[tid + 384]);
}

// ---------------------------------------------------------------------------
// fin: BN affine + relu + max-over-k via hmax/hmin (affine monotone).
// ---------------------------------------------------------------------------
__global__ __launch_bounds__(256) void fin_kernel(const float* __restrict__ hmax_g,
                                                  const float* __restrict__ hmin_g,
                                                  const float* __restrict__ gsum,
                                                  const float* __restrict__ gsq,
                                                  const float* __restrict__ gamma,
                                                  const float* __restrict__ beta,
                                                  float* __restrict__ out) {
    const size_t e = (size_t)blockIdx.x * 256 + threadIdx.x;
    const int d = (int)(e & 127);
    const float inv_cnt = 1.0f / 131072.0f;
    float mu  = gsum[d] * inv_cnt;
    float var = gsq[d] * inv_cnt - mu * mu;
    float a   = gamma[d] * rsqrtf(var + 1e-5f);
    float sh  = fmaf(-mu, a, beta[d]);
    float hv  = (a >= 0.f) ? hmax_g[e] : hmin_g[e];
    float r   = fmaf(a, hv, sh);
    out[32768 + e] = r > 0.f ? r : 0.f;
}

// ---------------------------------------------------------------------------
extern "C" void kernel_launch(void* const* d_in, const int* in_sizes, int n_in,
                              void* d_out, int out_size, void* d_ws, size_t ws_size,
                              hipStream_t stream) {
    const float* events   = (const float*)d_in[0];
    const float* features = (const float*)d_in[1];
    const float* W        = (const float*)d_in[2];
    const float* bias     = (const float*)d_in[3];
    const float* gamma    = (const float*)d_in[4];
    const float* beta     = (const float*)d_in[5];
    float* out = (float*)d_out;
    char* ws = (char*)d_ws;

    int*   down_idx = (int*)ws;                          // 32768 B
    float* gsum     = (float*)(ws + 32768);              // 512 B
    float* gsq      = (float*)(ws + 33280);              // 512 B
    int*   prog     = (int*)(ws + 33792);                // 256 B (4 used)
    float* hmaxg    = (float*)(ws + 40960);              // 4 MB
    float* hming    = hmaxg + (size_t)4 * M_PTS * OUT_CH;// 4 MB

    (void)hipMemsetAsync(gsum, 0, 1024, stream);
    (void)hipMemsetAsync(prog, 0, 256, stream);

    // LDS: max(fps 139328, worker 141440) = 141440
    const size_t lds = 141440;
    fused_kernel<<<256, 512, lds, stream>>>((const float4*)events, (const float4*)features,
                                            W, bias, down_idx, prog, (float4*)out,
                                            hmaxg, hming, gsum, gsq);

    fin_kernel<<<4096, 256, 0, stream>>>(hmaxg, hming, gsum, gsq, gamma, beta, out);
}

// Round 16
// 2375.544 us; speedup vs baseline: 1.5422x; 1.5422x over previous
//
#include <hip/hip_runtime.h>

#define N_PTS 8192
#define M_PTS 2048
#define K_NN 16
#define IN_CH 64
#define G_CH 68
#define OUT_CH 128
#define KCAP 128

// Unfusable fp32 ops: inline asm cannot be FMA-contracted by the compiler.
__device__ __forceinline__ float subrn(float a, float b) {
    float r; asm("v_sub_f32 %0, %1, %2" : "=v"(r) : "v"(a), "v"(b)); return r;
}
__device__ __forceinline__ float mulrn(float a, float b) {
    float r; asm("v_mul_f32 %0, %1, %2" : "=v"(r) : "v"(a), "v"(b)); return r;
}
__device__ __forceinline__ float addrn(float a, float b) {
    float r; asm("v_add_f32 %0, %1, %2" : "=v"(r) : "v"(a), "v"(b)); return r;
}
// numpy-exact fp32 squared distance: ((dx*dx + dy*dy) + dz*dz), per-op rounding.
__device__ __forceinline__ float sqdist_rn(float ax, float ay, float az,
                                           float bx, float by, float bz) {
    float dx = subrn(ax, bx);
    float dy = subrn(ay, by);
    float dz = subrn(az, bz);
    return addrn(addrn(mulrn(dx, dx), mulrn(dy, dy)), mulrn(dz, dz));
}

// Packed 2xfp32 ops (VOP3P). Each half is a plain IEEE fp32 op -> numerics
// bit-identical to scalar. Subtraction as a + (-b) (exact sign flip).
typedef float v2f __attribute__((ext_vector_type(2)));
__device__ __forceinline__ v2f pk_add(v2f a, v2f b) {
    v2f r; asm("v_pk_add_f32 %0, %1, %2" : "=v"(r) : "v"(a), "v"(b)); return r;
}
__device__ __forceinline__ v2f pk_mul(v2f a, v2f b) {
    v2f r; asm("v_pk_mul_f32 %0, %1, %2" : "=v"(r) : "v"(a), "v"(b)); return r;
}

// ---- DPP helpers ----------------------------------------------------------
template <int CTRL>
__device__ __forceinline__ float movdpp_f(float x) {
    int r = __builtin_amdgcn_mov_dpp(__float_as_int(x), CTRL, 0xf, 0xf, true);
    return __int_as_float(r);
}
// masked bcast stages for wave max: update_dpp old=0 (max with 0 safe, d>=0)
template <int CTRL, int RM>
__device__ __forceinline__ float dppmaxf_m(float x) {
    int r = __builtin_amdgcn_update_dpp(0, __float_as_int(x), CTRL, RM, 0xf, false);
    return fmaxf(x, __int_as_float(r));
}
// full 64-lane max -> valid in lane 63
__device__ __forceinline__ float wave_max64(float x) {
    x = fmaxf(x, movdpp_f<0xB1>(x));   // quad_perm xor1
    x = fmaxf(x, movdpp_f<0x4E>(x));   // quad_perm xor2
    x = fmaxf(x, movdpp_f<0x141>(x));  // row_half_mirror
    x = fmaxf(x, movdpp_f<0x140>(x));  // row_mirror
    x = dppmaxf_m<0x142, 0xa>(x);      // row_bcast15 -> rows 1,3
    x = dppmaxf_m<0x143, 0xc>(x);      // row_bcast31 -> lane63 full
    return x;
}
// 8-lane-group max (lane%8-aligned)
__device__ __forceinline__ float group8_max(float x) {
    x = fmaxf(x, movdpp_f<0xB1>(x));
    x = fmaxf(x, movdpp_f<0x4E>(x));
    x = fmaxf(x, movdpp_f<0x141>(x));
    return x;
}

// ---------------------------------------------------------------------------
// Kernel 1: FPS (structural floor: serial 2047-iteration chain, 2 barriers +
// DPP reduce + LDS round-trips per iteration; ~2020 us measured across all
// structural variants R8-R13).
// ---------------------------------------------------------------------------
__global__ __launch_bounds__(512, 2) void fps_kernel(const float4* __restrict__ events4,
                                                     int* __restrict__ down_idx,
                                                     float4* __restrict__ out_de) {
    extern __shared__ char smem[];
    float*  rv   = (float*)smem;                   // 8 floats: wave-max partials
    int*    wsl  = (int*)(smem + 32);              // 2 ints: winner slot (parity)
    int*    ssel = (int*)(smem + 64);              // 2048 ints
    float4* spt  = (float4*)(smem + 64 + 4 * M_PTS);

    const int b = blockIdx.x;
    const int tid = threadIdx.x;
    const int wave = tid >> 6;
    const int lane = tid & 63;
    const float4* ev = events4 + (size_t)b * N_PTS;

    for (int i = tid; i < N_PTS; i += 512) spt[i] = ev[i];
    if (tid == 0) { ssel[0] = 0; wsl[0] = 0x7fffffff; wsl[1] = 0x7fffffff; }
    __syncthreads();

    v2f px[8], py[8], pz[8];
    float dist[16];
#pragma unroll
    for (int pp = 0; pp < 8; ++pp) {
        float4 f0 = spt[(2 * pp) * 512 + tid];
        float4 f1 = spt[(2 * pp + 1) * 512 + tid];
        px[pp] = (v2f){f0.x, f1.x};
        py[pp] = (v2f){f0.y, f1.y};
        pz[pp] = (v2f){f0.z, f1.z};
        dist[2 * pp] = 1e10f; dist[2 * pp + 1] = 1e10f;   // reference init
    }

    int last = 0;
    for (int i = 1; i < M_PTS; ++i) {
        float4 L = spt[last];                     // uniform ds_read_b128
        const float nlx = -L.x, nly = -L.y, nlz = -L.z;   // exact sign flips
        const v2f nx2 = (v2f){nlx, nlx};
        const v2f ny2 = (v2f){nly, nly};
        const v2f nz2 = (v2f){nlz, nlz};
#pragma unroll
        for (int pp = 0; pp < 8; ++pp) {
            v2f dx = pk_add(px[pp], nx2);         // == px - lx, exact
            v2f dy = pk_add(py[pp], ny2);
            v2f dz = pk_add(pz[pp], nz2);
            v2f s  = pk_add(pk_add(pk_mul(dx, dx), pk_mul(dy, dy)), pk_mul(dz, dz));
            dist[2 * pp]     = fminf(dist[2 * pp],     s.x);
            dist[2 * pp + 1] = fminf(dist[2 * pp + 1], s.y);
        }
        float t0[8];
#pragma unroll
        for (int j = 0; j < 8; ++j) t0[j] = fmaxf(dist[2 * j], dist[2 * j + 1]);
#pragma unroll
        for (int j = 0; j < 4; ++j) t0[j] = fmaxf(t0[2 * j], t0[2 * j + 1]);
        float bd = fmaxf(fmaxf(t0[0], t0[1]), fmaxf(t0[2], t0[3]));

        float wm = wave_max64(bd);
        if (lane == 63) rv[wave] = wm;
        __syncthreads();                          // B1
        float bm = group8_max(rv[lane & 7]);      // uniform block max

        if (bd == bm) {
            int jm = 0;
#pragma unroll
            for (int j = 15; j >= 0; --j) if (dist[j] == bd) jm = j;
            atomicMin(&wsl[i & 1], jm * 512 + tid);
        }
        __syncthreads();                          // B2
        last = wsl[i & 1];
        if (tid == 0) { ssel[i] = last; wsl[(i + 1) & 1] = 0x7fffffff; }
    }
    __syncthreads();

    for (int i = tid; i < M_PTS; i += 512) {
        int s = ssel[i];
        down_idx[b * M_PTS + i] = s;
        out_de[(size_t)b * M_PTS + i] = spt[s];
    }
}

// ---------------------------------------------------------------------------
// Kernel 2: 16-NN, threshold algorithm with adjacent-pair LDS reads.
// ---------------------------------------------------------------------------
__global__ __launch_bounds__(256, 1) void knn_kernel(const float4* __restrict__ events4,
                                                     const int* __restrict__ down_idx,
                                                     int* __restrict__ knn_idx) {
    extern __shared__ char smem[];
    float2* sxy  = (float2*)smem;                    // 8192 float2 (64 KB)
    float*  sz   = (float*)(smem + N_PTS * 8);       // 8192 floats (32 KB)
    float*  cd   = sz + N_PTS;                       // 32*KCAP floats
    int*    ci   = (int*)(cd + 32 * KCAP);           // 32*KCAP ints
    int*    scnt = (int*)(ci + 32 * KCAP);           // 32 ints

    const int b    = blockIdx.x >> 6;
    const int qg   = blockIdx.x & 63;
    const int tid  = threadIdx.x;
    const int ql   = tid >> 3;
    const int part = tid & 7;

    const float4* ev = events4 + (size_t)b * N_PTS;
    for (int i = tid; i < N_PTS; i += 256) {
        float4 e = ev[i];
        sxy[i] = (float2){e.x, e.y}; sz[i] = e.z;
    }
    if (tid < 32) scnt[tid] = 0;
    __syncthreads();

    const int q  = qg * 32 + ql;
    const int qi = down_idx[b * M_PTS + q];
    const float2 qxy = sxy[qi];
    const float qx = qxy.x, qy = qxy.y, qz = sz[qi];

    const float4* sxy4 = (const float4*)sxy;
    const float2* sz2  = (const float2*)sz;

    // pass 1: branchless top-2 smallest per lane, 2 adjacent pts per iter
    float m1 = 1e30f, m2 = 1e30f;
    for (int i = 0; i < N_PTS / 16; ++i) {
        const int ph = i * 8 + part;              // pair index; pts 2ph, 2ph+1
        float4 xy = sxy4[ph];
        float2 zz = sz2[ph];
        float d0 = sqdist_rn(xy.x, xy.y, zz.x, qx, qy, qz);
        float d1 = sqdist_rn(xy.z, xy.w, zz.y, qx, qy, qz);
        float lo0 = fminf(m1, d0);
        m2 = fminf(m2, fmaxf(m1, d0));
        m1 = lo0;
        float lo1 = fminf(m1, d1);
        m2 = fminf(m2, fmaxf(m1, d1));
        m1 = lo1;
    }
    const float T = group8_max(m2);

    // pass 2: compact candidates (same paired reads)
    for (int i = 0; i < N_PTS / 16; ++i) {
        const int ph = i * 8 + part;
        float4 xy = sxy4[ph];
        float2 zz = sz2[ph];
        float d0 = sqdist_rn(xy.x, xy.y, zz.x, qx, qy, qz);
        float d1 = sqdist_rn(xy.z, xy.w, zz.y, qx, qy, qz);
        if (d0 <= T) {
            int pos = atomicAdd(&scnt[ql], 1);
            if (pos < KCAP) { cd[ql * KCAP + pos] = d0; ci[ql * KCAP + pos] = 2 * ph; }
        }
        if (d1 <= T) {
            int pos = atomicAdd(&scnt[ql], 1);
            if (pos < KCAP) { cd[ql * KCAP + pos] = d1; ci[ql * KCAP + pos] = 2 * ph + 1; }
        }
    }
    __syncthreads();

    if (part == 0) {
        float nd[16]; int ni[16];
#pragma unroll
        for (int j = 0; j < 16; ++j) { nd[j] = 1e30f; ni[j] = 0x7fffffff; }
        float wmax = 1e30f; int widx = 0x7fffffff; int wslot = 0;
        const int n = scnt[ql];
        const int lim = (n <= KCAP) ? n : 0;
        for (int t = 0; t < lim; ++t) {
            float d = cd[ql * KCAP + t];
            int   p = ci[ql * KCAP + t];
            if (d < wmax || (d == wmax && p < widx)) {
#pragma unroll
                for (int j = 0; j < 16; ++j) if (j == wslot) { nd[j] = d; ni[j] = p; }
                float m_ = -1.0f; int mix_ = -1; int ms_ = 0;
#pragma unroll
                for (int j = 0; j < 16; ++j)
                    if (nd[j] > m_ || (nd[j] == m_ && ni[j] > mix_)) { m_ = nd[j]; mix_ = ni[j]; ms_ = j; }
                wmax = m_; widx = mix_; wslot = ms_;
            }
        }
        if (n > KCAP) {   // exact serial fallback (never expected)
            for (int p = 0; p < N_PTS; ++p) {
                float2 pxy = sxy[p];
                float d = sqdist_rn(pxy.x, pxy.y, sz[p], qx, qy, qz);
                if (d < wmax || (d == wmax && p < widx)) {
#pragma unroll
                    for (int j = 0; j < 16; ++j) if (j == wslot) { nd[j] = d; ni[j] = p; }
                    float m_ = -1.0f; int mix_ = -1; int ms_ = 0;
#pragma unroll
                    for (int j = 0; j < 16; ++j)
                        if (nd[j] > m_ || (nd[j] == m_ && ni[j] > mix_)) { m_ = nd[j]; mix_ = ni[j]; ms_ = j; }
                    wmax = m_; widx = mix_; wslot = ms_;
                }
            }
        }
        int* out = knn_idx + ((size_t)(b * M_PTS + q)) * K_NN;
#pragma unroll
        for (int j = 0; j < 16; ++j) out[j] = ni[j];
    }
}

// ---------------------------------------------------------------------------
// Kernel 3: gather + per-query (16x68)@(68x128) matmul + bias. Thread =
// (d, query-slot); 2 queries staged per round; float4 staging.
// ---------------------------------------------------------------------------
__global__ __launch_bounds__(256, 2) void gmm_kernel(const float4* __restrict__ events4,
                                                     const float4* __restrict__ feat4,
                                                     const float* __restrict__ W,
                                                     const float* __restrict__ bias,
                                                     const int* __restrict__ knn_idx,
                                                     const float4* __restrict__ de4,
                                                     float* __restrict__ hmax_g,
                                                     float* __restrict__ hmin_g,
                                                     float* __restrict__ gsum,
                                                     float* __restrict__ gsq) {
    __shared__ __align__(16) float4 sg4[2 * 16 * 17];   // 2 queries x 16 k x 17
    __shared__ float scomb[2 * OUT_CH];

    const int b   = blockIdx.x >> 7;
    const int qg  = blockIdx.x & 127;
    const int tid = threadIdx.x;
    const int d   = tid & 127;
    const int qs  = tid >> 7;          // query slot 0/1

    float w[G_CH];
#pragma unroll
    for (int c = 0; c < G_CH; ++c) w[c] = W[c * OUT_CH + d];
    const float breg = bias[d];

    float ssum = 0.f, ssq = 0.f;

    for (int r = 0; r < 8; ++r) {
        const int base = b * M_PTS + qg * 16 + 2 * r;
        for (int j4 = tid; j4 < 2 * 16 * 17; j4 += 256) {
            int qq = j4 / 272;
            int rem = j4 - qq * 272;
            int k = rem / 17;
            int c4 = rem - k * 17;
            int nb = knn_idx[(base + qq) * K_NN + k];
            float4 v;
            if (c4 == 0) {
                float4 e = events4[(size_t)b * N_PTS + nb];
                float4 d0 = de4[base + qq];
                v = (float4){e.x - d0.x, e.y - d0.y, e.z - d0.z, e.w - d0.w};
            } else {
                v = feat4[((size_t)(b * N_PTS + nb)) * 16 + (c4 - 1)];
            }
            sg4[j4] = v;
        }
        __syncthreads();

        float hmax = -1e30f, hmin = 1e30f;
#pragma unroll
        for (int k = 0; k < 16; ++k) {
            float acc = breg;
#pragma unroll
            for (int c4 = 0; c4 < 17; ++c4) {
                float4 g = sg4[qs * 272 + k * 17 + c4];
                acc = fmaf(g.x, w[4 * c4 + 0], acc);
                acc = fmaf(g.y, w[4 * c4 + 1], acc);
                acc = fmaf(g.z, w[4 * c4 + 2], acc);
                acc = fmaf(g.w, w[4 * c4 + 3], acc);
            }
            hmax = fmaxf(hmax, acc);
            hmin = fminf(hmin, acc);
            ssum += acc;
            ssq = fmaf(acc, acc, ssq);
        }
        const size_t o = (size_t)(base + qs) * OUT_CH + d;
        hmax_g[o] = hmax;
        hmin_g[o] = hmin;
        __syncthreads();   // protect sg before next staging
    }

    if (qs == 1) { scomb[d] = ssum; scomb[OUT_CH + d] = ssq; }
    __syncthreads();
    if (qs == 0) {
        atomicAdd(&gsum[d], ssum + scomb[d]);
        atomicAdd(&gsq[d],  ssq  + scomb[OUT_CH + d]);
    }
}

// ---------------------------------------------------------------------------
// Kernel 4: BN affine + relu + max-over-k via hmax/hmin (affine monotone).
// ---------------------------------------------------------------------------
__global__ __launch_bounds__(256) void fin_kernel(const float* __restrict__ hmax_g,
                                                  const float* __restrict__ hmin_g,
                                                  const float* __restrict__ gsum,
                                                  const float* __restrict__ gsq,
                                                  const float* __restrict__ gamma,
                                                  const float* __restrict__ beta,
                                                  float* __restrict__ out) {
    const size_t e = (size_t)blockIdx.x * 256 + threadIdx.x;
    const int d = (int)(e & 127);
    const float inv_cnt = 1.0f / 131072.0f;
    float mu  = gsum[d] * inv_cnt;
    float var = gsq[d] * inv_cnt - mu * mu;
    float a   = gamma[d] * rsqrtf(var + 1e-5f);
    float sh  = fmaf(-mu, a, beta[d]);
    float hv  = (a >= 0.f) ? hmax_g[e] : hmin_g[e];
    float r   = fmaf(a, hv, sh);
    out[32768 + e] = r > 0.f ? r : 0.f;
}

// ---------------------------------------------------------------------------
extern "C" void kernel_launch(void* const* d_in, const int* in_sizes, int n_in,
                              void* d_out, int out_size, void* d_ws, size_t ws_size,
                              hipStream_t stream) {
    const float* events   = (const float*)d_in[0];
    const float* features = (const float*)d_in[1];
    const float* W        = (const float*)d_in[2];
    const float* bias     = (const float*)d_in[3];
    const float* gamma    = (const float*)d_in[4];
    const float* beta     = (const float*)d_in[5];
    float* out = (float*)d_out;
    char* ws = (char*)d_ws;

    int*   down_idx = (int*)ws;                          // 32768 B
    int*   knn_idx  = (int*)(ws + 32768);                // 524288 B
    float* gsum     = (float*)(ws + 32768 + 524288);     // 512 B
    float* gsq      = gsum + OUT_CH;                     // 512 B
    float* hmaxg    = (float*)(ws + 558080);             // 4 MB
    float* hming    = hmaxg + (size_t)4 * M_PTS * OUT_CH;// 4 MB

    (void)hipMemsetAsync(gsum, 0, 2 * OUT_CH * sizeof(float), stream);

    const size_t fps_lds = 64 + 4 * M_PTS + (size_t)N_PTS * sizeof(float4); // 139328
    fps_kernel<<<4, 512, fps_lds, stream>>>((const float4*)events, down_idx, (float4*)out);

    const size_t knn_lds = (size_t)N_PTS * 8 + (size_t)N_PTS * 4
                         + (size_t)32 * KCAP * 8 + 128;                      // 131200
    knn_kernel<<<256, 256, knn_lds, stream>>>((const float4*)events, down_idx, knn_idx);

    gmm_kernel<<<512, 256, 0, stream>>>((const float4*)events, (const float4*)features,
                                        W, bias, knn_idx, (const float4*)out,
                                        hmaxg, hming, gsum, gsq);

    fin_kernel<<<4096, 256, 0, stream>>>(hmaxg, hming, gsum, gsq, gamma, beta, out);
}